// Round 14
// baseline (468.008 us; speedup 1.0000x reference)
//
#include <hip/hip_runtime.h>

// ---------------- types / helpers ----------------
typedef __bf16 bf16x8 __attribute__((ext_vector_type(8)));
typedef float f32x4 __attribute__((ext_vector_type(4)));
typedef unsigned short u16x8 __attribute__((ext_vector_type(8)));

__device__ __forceinline__ unsigned short f2bf(float f) {
  union { float f; unsigned int u; } v; v.f = f;
  unsigned int r = v.u + 0x7fffu + ((v.u >> 16) & 1u);  // RNE
  return (unsigned short)(r >> 16);
}

__device__ __forceinline__ void async16(const unsigned short* g, unsigned short* l) {
  __builtin_amdgcn_global_load_lds(
      (const __attribute__((address_space(1))) unsigned int*)g,
      (__attribute__((address_space(3))) unsigned int*)l, 16, 0, 0);
}

// ---------------- fused converts: all weights + memory + bias concat, ONE launch ------
__global__ void cvt_all(const float* __restrict__ q_w, const float* __restrict__ k_w,
                        const float* __restrict__ v_w, const float* __restrict__ o_w,
                        const float* __restrict__ f1w, const float* __restrict__ f2w,
                        const float* __restrict__ mem,
                        const float* __restrict__ q_b, const float* __restrict__ k_b,
                        const float* __restrict__ v_b,
                        unsigned short* __restrict__ WQ, unsigned short* __restrict__ WK,
                        unsigned short* __restrict__ WV, unsigned short* __restrict__ WO,
                        unsigned short* __restrict__ WF1, unsigned short* __restrict__ WF2,
                        unsigned short* __restrict__ MEMB, float* __restrict__ QKVB) {
  const int bid = blockIdx.x;
  const float* src; unsigned short* dst; float scale = 1.f; int base;
  if (bid < 1024)       { src = q_w; dst = WQ;  scale = 0.125f; base = 0; }
  else if (bid < 2048)  { src = k_w; dst = WK;  base = 1024; }
  else if (bid < 3072)  { src = v_w; dst = WV;  base = 2048; }
  else if (bid < 4096)  { src = o_w; dst = WO;  base = 3072; }
  else if (bid < 8192)  { src = f1w; dst = WF1; base = 4096; }
  else if (bid < 12288) { src = f2w; dst = WF2; base = 8192; }
  else if (bid < 13312) { src = mem; dst = MEMB; base = 12288; }
  else {  // bias concat (12 blocks, 3072 elems), q-bias pre-scaled
    const int i = (bid - 13312) * 256 + threadIdx.x;
    QKVB[i] = (i < 1024) ? q_b[i] * 0.125f : (i < 2048 ? k_b[i - 1024] : v_b[i - 2048]);
    return;
  }
  const int i = (bid - base) * 256 + threadIdx.x;
  float4 v = ((const float4*)src)[i];
  ushort4 o;
  o.x = f2bf(v.x * scale); o.y = f2bf(v.y * scale);
  o.z = f2bf(v.z * scale); o.w = f2bf(v.w * scale);
  ((ushort4*)dst)[i] = o;
}

// ---------------- LayerNorm (per 1024-row) -> bf16 ----------------
template <int PREFILL>
__global__ __launch_bounds__(256) void ln_bf16(
    const float* __restrict__ src, unsigned short* __restrict__ dst,
    const float* __restrict__ g, const float* __restrict__ be,
    const float* __restrict__ fbias, float* __restrict__ dout) {
  const int row = blockIdx.x, tid = threadIdx.x;
  const float4 v = ((const float4*)(src + (size_t)row * 1024))[tid];
  if (PREFILL) {
    const float4 fb = ((const float4*)fbias)[tid];
    float4 r;
    r.x = v.x + fb.x; r.y = v.y + fb.y; r.z = v.z + fb.z; r.w = v.w + fb.w;
    ((float4*)(dout + (size_t)row * 1024))[tid] = r;
  }
  float s = v.x + v.y + v.z + v.w;
  float qq = v.x * v.x + v.y * v.y + v.z * v.z + v.w * v.w;
#pragma unroll
  for (int off = 32; off; off >>= 1) { s += __shfl_xor(s, off); qq += __shfl_xor(qq, off); }
  __shared__ float ps[4], pq[4];
  const int w = tid >> 6, lane = tid & 63;
  if (lane == 0) { ps[w] = s; pq[w] = qq; }
  __syncthreads();
  if (tid == 0) { ps[0] = ps[0] + ps[1] + ps[2] + ps[3]; pq[0] = pq[0] + pq[1] + pq[2] + pq[3]; }
  __syncthreads();
  const float mu = ps[0] * (1.f / 1024.f);
  const float var = pq[0] * (1.f / 1024.f) - mu * mu;
  const float rs = rsqrtf(var + 1e-5f);
  const float4 gv = ((const float4*)g)[tid];
  const float4 bv = ((const float4*)be)[tid];
  ushort4 o;
  o.x = f2bf((v.x - mu) * rs * gv.x + bv.x);
  o.y = f2bf((v.y - mu) * rs * gv.y + bv.y);
  o.z = f2bf((v.z - mu) * rs * gv.z + bv.z);
  o.w = f2bf((v.w - mu) * rs * gv.w + bv.w);
  ((ushort4*)(dst + (size_t)row * 1024))[tid] = o;
}

// ---------------- GEMM: C[M,N] = A[M,K] @ B[N,K]^T (+ bias), m97-style, BK=64 --------
// SESSION LEDGER (r1-13): deep-pipeline 1-blk/CU engines all fail (latency-bound);
// 256-thr kernel at 3-6 blk/CU wins via m114 implicit wave overlap. r10: LESS work
// per barrier = worse. r12: MORE work per barrier (BK=64) = -24us; all GEMMs < 95us.
// Per-op optima: fc1 BNT=128@1536; fc2 BNT=128 splitK2@768; outproj BNT=64@768.
// (256,4): reg cap 128 — no spill ((256,8) scratch catastrophe, r2).
#define KOFF 6291456ull
#define VOFF 13631488ull
template <int EPI, int BNT>
__global__ __launch_bounds__(256, 4) void gemm_bt(
    const unsigned short* __restrict__ A, const unsigned short* __restrict__ Bw,
    const float* __restrict__ bias, const float* __restrict__ resid,
    void* __restrict__ Cout, int M, int N, int K, int lda, int ldb, int NBN, int WM) {
  constexpr int NJ = BNT / 32;       // B-frags per wave; wave covers 16*NJ cols
  constexpr int BS = BNT * 32;       // u16 per B slab
  __shared__ __align__(16) unsigned short lA[2 * 128 * 32];  // [slab][128][32]
  __shared__ __align__(16) unsigned short lB[2 * BS];        // [slab][BNT][32]
  const int tid = threadIdx.x;
  const int w = tid >> 6, lane = tid & 63;
  const int lr = lane & 15, lq = lane >> 4;
  const int l = blockIdx.x;
  const int xcd = l & 7, r = l >> 3;
  const int bm = xcd * WM + (r % WM);
  const int rest = r / WM;
  const int bn = rest % NBN;
  const size_t koff = (size_t)(rest / NBN) * K;  // split-K offset (K = per-block K)
  const unsigned short* Ab = A + (size_t)bm * 128 * lda + koff;
  const unsigned short* Bb = Bw + (size_t)bn * BNT * ldb + koff;
  const int wm = (w & 1) << 6;
  const int wn = (w >> 1) * (16 * NJ);
  f32x4 acc[4][NJ] = {};
  const int kiters = K >> 6;         // BK=64
  const int c0 = tid, c1 = 256 + tid;
  const int r0 = c0 >> 2, o0 = (c0 & 3) << 3;
  const int r1 = c1 >> 2, o1 = (c1 & 3) << 3;
  for (int kt = 0; kt < kiters; ++kt) {
    const int kb = kt << 6;
    __syncthreads();
#pragma unroll
    for (int s = 0; s < 2; ++s) {
      const int kc = kb + s * 32;
      async16(Ab + (size_t)r0 * lda + kc + o0, lA + s * 4096 + c0 * 8);
      async16(Ab + (size_t)r1 * lda + kc + o1, lA + s * 4096 + c1 * 8);
      async16(Bb + (size_t)r0 * ldb + kc + o0, lB + s * BS + c0 * 8);
      if (BNT == 128) async16(Bb + (size_t)r1 * ldb + kc + o1, lB + s * BS + c1 * 8);
    }
    __syncthreads();
#pragma unroll
    for (int s = 0; s < 2; ++s) {
      bf16x8 af[4], bfr[NJ];
#pragma unroll
      for (int i = 0; i < 4; ++i)
        af[i] = *(const bf16x8*)(lA + s * 4096 + (wm + i * 16 + lr) * 32 + lq * 8);
#pragma unroll
      for (int j = 0; j < NJ; ++j)
        bfr[j] = *(const bf16x8*)(lB + s * BS + (wn + j * 16 + lr) * 32 + lq * 8);
#pragma unroll
      for (int i = 0; i < 4; ++i)
#pragma unroll
        for (int j = 0; j < NJ; ++j)
          acc[i][j] = __builtin_amdgcn_mfma_f32_16x16x32_bf16(af[i], bfr[j], acc[i][j], 0, 0, 0);
    }
  }
  const int which = (bn * BNT) >> 10;  // EPI5: 0=Q,1=K,2=V (block-uniform; 1024%BNT==0)
#pragma unroll
  for (int i = 0; i < 4; ++i) {
#pragma unroll
    for (int j = 0; j < NJ; ++j) {
      const int colg = bn * BNT + wn + j * 16 + lr;
      const float bi = (EPI == 6) ? 0.f : bias[colg];
      const int rowg0 = bm * 128 + wm + i * 16 + lq * 4;
#pragma unroll
      for (int r2 = 0; r2 < 4; ++r2) {
        const int rowg = rowg0 + r2;
        const float val = acc[i][j][r2] + bi;
        if (EPI == 5) {
          const int t = rowg >> 4, bb = rowg & 15;
          const int hh = (colg >> 6) & 15, dd = colg & 63;
          const size_t nn = (size_t)(bb * 16 + hh);
          unsigned short* q16 = (unsigned short*)Cout;
          if (which == 0) {
            if (rowg >= 1024) q16[(nn * 384 + (t - 64)) * 64 + dd] = f2bf(val);
          } else if (which == 1) {
            q16[KOFF + (nn * 448 + t) * 64 + dd] = f2bf(val);
          } else {
            q16[VOFF + (nn * 448 + t) * 64 + dd] = f2bf(val);
          }
        } else {
          const size_t idx = (size_t)rowg * N + colg;
          if (EPI == 2) ((float*)Cout)[idx] = val + resid[idx];
          else if (EPI == 3) ((unsigned short*)Cout)[idx] = f2bf(fmaxf(val, 0.f));
          else if (EPI == 6) atomicAdd(&((float*)Cout)[idx], acc[i][j][r2]);
        }
      }
    }
  }
}

// ---------------- V transpose: vb[n][t][d] -> vt[n][d][t] ----------------
__global__ __launch_bounds__(256) void vtrans(const unsigned short* __restrict__ vb,
                                              unsigned short* __restrict__ vt) {
  __shared__ __align__(16) unsigned short ls[64][80];
  const int kc = blockIdx.x, n = blockIdx.y;
  const int tid = threadIdx.x;
#pragma unroll
  for (int i = 0; i < 2; ++i) {
    const int c = i * 256 + tid;
    const int kk = c >> 3, dc = (c & 7) << 3;
    u16x8 val = *(const u16x8*)(vb + ((size_t)n * 448 + kc * 64 + kk) * 64 + dc);
    *(u16x8*)&ls[kk][dc] = val;
  }
  __syncthreads();
#pragma unroll
  for (int i = 0; i < 2; ++i) {
    const int c = i * 256 + tid;
    const int d = c >> 3, kx = (c & 7) << 3;
    u16x8 o;
#pragma unroll
    for (int j = 0; j < 8; ++j) o[j] = ls[kx + j][d];
    *(u16x8*)(vt + ((size_t)n * 64 + d) * 448 + kc * 64 + kx) = o;
  }
}

// ---------------- fused attention, S^T formulation, 4 waves/block ----------------
// r13: variance pass eliminated via sum(p^2) identity (102->94.5us).
// ROUND 14: shorten the serial chain further.
//  (a) DEFER s2 normalization past PV: P stores unnormalized masked e (bf16 range
//      identical, e<=1); scale applied after transpose where each lane owns one
//      q-row (4 LDS reads + 1 div + 4 muls). Deletes one barrier + one LDS
//      reduction round-trip + 28 muls from the chain (R2 reduction rides the
//      existing pre-PV barrier).
//  (b) mask compare hoisted: acc*inv < thr  <=>  acc < thr*s (one mul, saves 28).
#define PST 468  // P row stride (u16): dword stride 234 == 10 mod 32 -> ~2-way (free)
__global__ __launch_bounds__(256) void attn_kernel(
    const unsigned short* __restrict__ qt_, const unsigned short* __restrict__ kt_,
    const unsigned short* __restrict__ vt_, unsigned short* __restrict__ attn) {
  __shared__ __align__(16) unsigned short P[16 * PST];  // 14976 B
  __shared__ float Rm[4][16], Rs[4][16], Rc[4][16], Rv[4][16], R2[4][16];
  __shared__ __align__(16) float OT[4][16][17];         // per-wave transpose buffers
  const int id = blockIdx.x;
  const int xcd = id & 7, j0 = id >> 3;
  const int n = xcd * 32 + (j0 & 31), qt = j0 >> 5;  // qt 0..23
  const int b = n >> 4, h = n & 15;
  const int tid = threadIdx.x, w = tid >> 6, lane = tid & 63;
  const int lr = lane & 15, lq = lane >> 4;

  const unsigned short* qp = qt_ + ((size_t)n * 384 + qt * 16 + lr) * 64 + lq * 8;
  const bf16x8 q0 = *(const bf16x8*)qp;
  const bf16x8 q1 = *(const bf16x8*)(qp + 32);

  // phase 1: S^T for 7 k-tiles. acc[t][r] = S[q=lr][k = (w*7+t)*16 + 4*lq + r]
  f32x4 acc[7];
#pragma unroll
  for (int t = 0; t < 7; ++t) {
    const unsigned short* kp = kt_ + ((size_t)n * 448 + (w * 7 + t) * 16 + lr) * 64 + lq * 8;
    const bf16x8 k0 = *(const bf16x8*)kp;
    const bf16x8 k1 = *(const bf16x8*)(kp + 32);
    f32x4 a = {0.f, 0.f, 0.f, 0.f};
    a = __builtin_amdgcn_mfma_f32_16x16x32_bf16(k0, q0, a, 0, 0, 0);
    a = __builtin_amdgcn_mfma_f32_16x16x32_bf16(k1, q1, a, 0, 0, 0);
    acc[t] = a;
  }

  // ---- pass 1: row max ----
  f32x4 m4 = acc[0];
#pragma unroll
  for (int t = 1; t < 7; ++t) {
    m4[0] = fmaxf(m4[0], acc[t][0]); m4[1] = fmaxf(m4[1], acc[t][1]);
    m4[2] = fmaxf(m4[2], acc[t][2]); m4[3] = fmaxf(m4[3], acc[t][3]);
  }
  float m = fmaxf(fmaxf(m4[0], m4[1]), fmaxf(m4[2], m4[3]));
  m = fmaxf(m, __shfl_xor(m, 16));
  m = fmaxf(m, __shfl_xor(m, 32));
  if (lq == 0) Rm[w][lr] = m;
  __syncthreads();
  m = fmaxf(fmaxf(Rm[0][lr], Rm[1][lr]), fmaxf(Rm[2][lr], Rm[3][lr]));

  // ---- pass 2: exp in place; sum + nonzero count + sum of squares ----
  f32x4 s4 = {0.f, 0.f, 0.f, 0.f}, c4 = {0.f, 0.f, 0.f, 0.f}, q4 = {0.f, 0.f, 0.f, 0.f};
#pragma unroll
  for (int t = 0; t < 7; ++t) {
#pragma unroll
    for (int r = 0; r < 4; ++r) {
      const float e = __expf(acc[t][r] - m);
      acc[t][r] = e;
      s4[r] += e;
      q4[r] = fmaf(e, e, q4[r]);
      if (e > 0.f) c4[r] += 1.f;
    }
  }
  float s = (s4[0] + s4[1]) + (s4[2] + s4[3]);
  float cnt = (c4[0] + c4[1]) + (c4[2] + c4[3]);
  float e2 = (q4[0] + q4[1]) + (q4[2] + q4[3]);
  s += __shfl_xor(s, 16); s += __shfl_xor(s, 32);
  cnt += __shfl_xor(cnt, 16); cnt += __shfl_xor(cnt, 32);
  e2 += __shfl_xor(e2, 16); e2 += __shfl_xor(e2, 32);
  if (lq == 0) { Rs[w][lr] = s; Rc[w][lr] = cnt; Rv[w][lr] = e2; }
  __syncthreads();
  s = (Rs[0][lr] + Rs[1][lr]) + (Rs[2][lr] + Rs[3][lr]);
  cnt = (Rc[0][lr] + Rc[1][lr]) + (Rc[2][lr] + Rc[3][lr]);
  e2 = (Rv[0][lr] + Rv[1][lr]) + (Rv[2][lr] + Rv[3][lr]);
  const float inv = 1.f / s;
  const float mean = 1.f / cnt;  // sum_nz(p) == 1
  // variance identity: sum_nz((p-mean)^2) = sum(p^2) - 1/cnt
  const float dvs = fmaxf(e2 * inv * inv - mean, 0.f);
  const float thr = mean - 0.5f * sqrtf(dvs / (cnt - 1.f));
  const float thrs = thr * s;  // compare in e-space: e*inv < thr  <=>  e < thr*s

  // ---- pass 3: mask survivors in place + survivor partial sum ----
  // (row max always survives: p_max >= mean >= thr)
  f32x4 t4 = {0.f, 0.f, 0.f, 0.f};
#pragma unroll
  for (int t = 0; t < 7; ++t) {
#pragma unroll
    for (int r = 0; r < 4; ++r) {
      if (acc[t][r] < thrs) acc[t][r] = 0.f;
      t4[r] += acc[t][r];
    }
  }
  float s2 = (t4[0] + t4[1]) + (t4[2] + t4[3]);
  s2 += __shfl_xor(s2, 16); s2 += __shfl_xor(s2, 32);
  if (lq == 0) R2[w][lr] = s2;  // total read AFTER the P barrier (deferred norm)

  // ---- write P[q=lr][k] = masked e, UNNORMALIZED bf16 (e <= 1, same bf16 range) ----
#pragma unroll
  for (int t = 0; t < 7; ++t) {
#pragma unroll
    for (int rp = 0; rp < 4; rp += 2) {
      const unsigned int u =
          (unsigned int)f2bf(acc[t][rp]) | ((unsigned int)f2bf(acc[t][rp + 1]) << 16);
      *(unsigned int*)&P[lr * PST + (w * 7 + t) * 16 + lq * 4 + rp] = u;
    }
  }
  __syncthreads();  // covers both P and R2

  // phase 3: out^T[d][q] = V^T(64x448) . P(448x16). Wave w owns d-tile [w*16, w*16+16).
  f32x4 o = {0.f, 0.f, 0.f, 0.f};
#pragma unroll
  for (int c = 0; c < 14; ++c) {
    union { ushort4 hh[2]; bf16x8 v; } bf;
    bf.hh[0] = *(const ushort4*)&P[lr * PST + c * 32 + lq * 8];
    bf.hh[1] = *(const ushort4*)&P[lr * PST + c * 32 + lq * 8 + 4];
    const bf16x8 a = *(const bf16x8*)(vt_ + ((size_t)n * 64 + w * 16 + lr) * 448 + c * 32 + lq * 8);
    o = __builtin_amdgcn_mfma_f32_16x16x32_bf16(a, bf.v, o, 0, 0, 0);
  }

  // transpose 16x16 tile via wave-private LDS (no barrier: same-wave write->read),
  // then apply the deferred survivor normalization: each lane owns ONE q-row.
#pragma unroll
  for (int r = 0; r < 4; ++r) OT[w][lq * 4 + r][lr] = o[r];
  const int qrow = lane >> 2, dg = lane & 3;
  const float s2t = (R2[0][qrow] + R2[1][qrow]) + (R2[2][qrow] + R2[3][qrow]);
  const float i2 = 1.f / s2t;
  ushort4 ov;
  ov.x = f2bf(OT[w][dg * 4 + 0][qrow] * i2);
  ov.y = f2bf(OT[w][dg * 4 + 1][qrow] * i2);
  ov.z = f2bf(OT[w][dg * 4 + 2][qrow] * i2);
  ov.w = f2bf(OT[w][dg * 4 + 3][qrow] * i2);
  *(ushort4*)(attn + ((size_t)(qt * 16 + qrow) * 16 + b) * 1024 + h * 64 + w * 16 + dg * 4) = ov;
}

// ---------------- launch ----------------
extern "C" void kernel_launch(void* const* d_in, const int* in_sizes, int n_in,
                              void* d_out, int out_size, void* d_ws, size_t ws_size,
                              hipStream_t stream) {
  (void)in_sizes; (void)n_in; (void)out_size; (void)ws_size;
  const float* x    = (const float*)d_in[0];
  const float* mem  = (const float*)d_in[1];
  const float* q_w  = (const float*)d_in[2];
  const float* q_b  = (const float*)d_in[3];
  const float* k_w  = (const float*)d_in[4];
  const float* k_b  = (const float*)d_in[5];
  const float* v_w  = (const float*)d_in[6];
  const float* v_b  = (const float*)d_in[7];
  const float* o_w  = (const float*)d_in[8];
  const float* o_b  = (const float*)d_in[9];
  const float* ln1w = (const float*)d_in[10];
  const float* ln1b = (const float*)d_in[11];
  const float* f1w  = (const float*)d_in[12];
  const float* f1b  = (const float*)d_in[13];
  const float* f2w  = (const float*)d_in[14];
  const float* f2b  = (const float*)d_in[15];
  const float* ln2w = (const float*)d_in[16];
  const float* ln2b = (const float*)d_in[17];

  unsigned short* WQ   = (unsigned short*)d_ws;        // 3x 1048576 contiguous = fused B
  unsigned short* WK   = WQ + 1048576;
  unsigned short* WV   = WK + 1048576;
  unsigned short* WO   = WV + 1048576;
  unsigned short* WF1  = WO + 1048576;                 // 4194304
  unsigned short* WF2  = WF1 + 4194304;                // 4194304
  unsigned short* ABUF = WF2 + 4194304;                // 7340032 (mem rows 0..1023, xn rows 1024..7167)
  unsigned short* QB   = ABUF + 7340032;               // 6291456 [n][384][64]; KB/VB at KOFF/VOFF
  unsigned short* KB   = QB + 6291456;                 // 7340032 [n][448][64]
  unsigned short* VB   = KB + 7340032;                 // 7340032 [n][448][64]
  unsigned short* VT   = VB + 7340032;                 // 7340032 [n][64][448]
  unsigned short* ATTN = VT + 7340032;                 // 6291456
  float*          X2   = (float*)(ATTN + 6291456);     // 6291456 f32
  float*          QKVB = (float*)ATTN;                 // 3072 f32, dead before attn writes ATTN
  unsigned short* XN2  = ATTN;                         // alias (attn dead after out-proj)
  unsigned short* HB   = ABUF;                         // alias (A/q/k/v staging dead after attention)

  // all weight/memory converts + bias concat in ONE launch
  cvt_all<<<13324, 256, 0, stream>>>(q_w, k_w, v_w, o_w, f1w, f2w, mem, q_b, k_b, v_b,
                                     WQ, WK, WV, WO, WF1, WF2, ABUF, QKVB);

  // LN1 -> xn (rows 1024.. of ABUF)
  ln_bf16<0><<<6144, 256, 0, stream>>>(x, ABUF + 1048576, ln1w, ln1b, nullptr, nullptr);

  // fused QKV: [mem;xn] x [Wq;Wk;Wv]^T, head-major epilogue. NBM=56 -> WM=7, NBN=24.
  gemm_bt<5, 128><<<1344, 256, 0, stream>>>(ABUF, WQ, QKVB, nullptr, QB, 7168, 3072, 1024, 1024, 1024, 24, 7);

  vtrans<<<dim3(7, 256), 256, 0, stream>>>(VB, VT);
  attn_kernel<<<6144, 256, 0, stream>>>(QB, KB, VT, ATTN);

  // out-proj + residual -> X2 (f32). BNT=64: grid 768 = 8 XCD x (6 m x 16 n).
  gemm_bt<2, 64><<<768, 256, 0, stream>>>(ATTN, WO, o_b, x, X2, 6144, 1024, 1024, 1024, 1024, 16, 6);

  // LN2 -> xn2, and prefill d_out = X2 + fc2_bias (fc2 accumulates into it)
  ln_bf16<1><<<6144, 256, 0, stream>>>(X2, XN2, ln2w, ln2b, f2b, (float*)d_out);

  // FFN.
  // fc1: BNT=128, grid 1536 = 8 XCD x (6 m x 32 n).
  gemm_bt<3, 128><<<1536, 256, 0, stream>>>(XN2, WF1, f1b, nullptr, HB, 6144, 4096, 1024, 1024, 1024, 32, 6);
  // fc2: BNT=128, split-K 2, grid 768 = 8 XCD x (6 m x 8 n x 2 kz), per-block K=2048;
  //      atomicAdd f32 into ln2-prefilled d_out.
  gemm_bt<6, 128><<<768, 256, 0, stream>>>(HB, WF2, nullptr, nullptr, d_out, 6144, 1024, 2048, 4096, 4096, 8, 6);
}

// Round 15
// 454.743 us; speedup vs baseline: 1.0292x; 1.0292x over previous
//
#include <hip/hip_runtime.h>

// ---------------- types / helpers ----------------
typedef __bf16 bf16x8 __attribute__((ext_vector_type(8)));
typedef float f32x4 __attribute__((ext_vector_type(4)));
typedef unsigned short u16x8 __attribute__((ext_vector_type(8)));

__device__ __forceinline__ unsigned short f2bf(float f) {
  union { float f; unsigned int u; } v; v.f = f;
  unsigned int r = v.u + 0x7fffu + ((v.u >> 16) & 1u);  // RNE
  return (unsigned short)(r >> 16);
}

__device__ __forceinline__ void async16(const unsigned short* g, unsigned short* l) {
  __builtin_amdgcn_global_load_lds(
      (const __attribute__((address_space(1))) unsigned int*)g,
      (__attribute__((address_space(3))) unsigned int*)l, 16, 0, 0);
}

// ---------------- fused converts: all weights + memory + bias concat, ONE launch ------
__global__ void cvt_all(const float* __restrict__ q_w, const float* __restrict__ k_w,
                        const float* __restrict__ v_w, const float* __restrict__ o_w,
                        const float* __restrict__ f1w, const float* __restrict__ f2w,
                        const float* __restrict__ mem,
                        const float* __restrict__ q_b, const float* __restrict__ k_b,
                        const float* __restrict__ v_b,
                        unsigned short* __restrict__ WQ, unsigned short* __restrict__ WK,
                        unsigned short* __restrict__ WV, unsigned short* __restrict__ WO,
                        unsigned short* __restrict__ WF1, unsigned short* __restrict__ WF2,
                        unsigned short* __restrict__ MEMB, float* __restrict__ QKVB) {
  const int bid = blockIdx.x;
  const float* src; unsigned short* dst; float scale = 1.f; int base;
  if (bid < 1024)       { src = q_w; dst = WQ;  scale = 0.125f; base = 0; }
  else if (bid < 2048)  { src = k_w; dst = WK;  base = 1024; }
  else if (bid < 3072)  { src = v_w; dst = WV;  base = 2048; }
  else if (bid < 4096)  { src = o_w; dst = WO;  base = 3072; }
  else if (bid < 8192)  { src = f1w; dst = WF1; base = 4096; }
  else if (bid < 12288) { src = f2w; dst = WF2; base = 8192; }
  else if (bid < 13312) { src = mem; dst = MEMB; base = 12288; }
  else {  // bias concat (12 blocks, 3072 elems), q-bias pre-scaled
    const int i = (bid - 13312) * 256 + threadIdx.x;
    QKVB[i] = (i < 1024) ? q_b[i] * 0.125f : (i < 2048 ? k_b[i - 1024] : v_b[i - 2048]);
    return;
  }
  const int i = (bid - base) * 256 + threadIdx.x;
  float4 v = ((const float4*)src)[i];
  ushort4 o;
  o.x = f2bf(v.x * scale); o.y = f2bf(v.y * scale);
  o.z = f2bf(v.z * scale); o.w = f2bf(v.w * scale);
  ((ushort4*)dst)[i] = o;
}

// ---------------- LayerNorm (per 1024-row) -> bf16 ----------------
template <int PREFILL>
__global__ __launch_bounds__(256) void ln_bf16(
    const float* __restrict__ src, unsigned short* __restrict__ dst,
    const float* __restrict__ g, const float* __restrict__ be,
    const float* __restrict__ fbias, float* __restrict__ dout) {
  const int row = blockIdx.x, tid = threadIdx.x;
  const float4 v = ((const float4*)(src + (size_t)row * 1024))[tid];
  if (PREFILL) {
    const float4 fb = ((const float4*)fbias)[tid];
    float4 r;
    r.x = v.x + fb.x; r.y = v.y + fb.y; r.z = v.z + fb.z; r.w = v.w + fb.w;
    ((float4*)(dout + (size_t)row * 1024))[tid] = r;
  }
  float s = v.x + v.y + v.z + v.w;
  float qq = v.x * v.x + v.y * v.y + v.z * v.z + v.w * v.w;
#pragma unroll
  for (int off = 32; off; off >>= 1) { s += __shfl_xor(s, off); qq += __shfl_xor(qq, off); }
  __shared__ float ps[4], pq[4];
  const int w = tid >> 6, lane = tid & 63;
  if (lane == 0) { ps[w] = s; pq[w] = qq; }
  __syncthreads();
  if (tid == 0) { ps[0] = ps[0] + ps[1] + ps[2] + ps[3]; pq[0] = pq[0] + pq[1] + pq[2] + pq[3]; }
  __syncthreads();
  const float mu = ps[0] * (1.f / 1024.f);
  const float var = pq[0] * (1.f / 1024.f) - mu * mu;
  const float rs = rsqrtf(var + 1e-5f);
  const float4 gv = ((const float4*)g)[tid];
  const float4 bv = ((const float4*)be)[tid];
  ushort4 o;
  o.x = f2bf((v.x - mu) * rs * gv.x + bv.x);
  o.y = f2bf((v.y - mu) * rs * gv.y + bv.y);
  o.z = f2bf((v.z - mu) * rs * gv.z + bv.z);
  o.w = f2bf((v.w - mu) * rs * gv.w + bv.w);
  ((ushort4*)(dst + (size_t)row * 1024))[tid] = o;
}

// ---------------- GEMM: C[M,N] = A[M,K] @ B[N,K]^T (+ bias), m97-style, BK=64 --------
// SESSION LEDGER (r1-14): deep-pipeline 1-blk/CU engines all fail (latency-bound);
// 256-thr kernel at 3-6 blk/CU wins via m114 implicit wave overlap. r10: LESS work
// per barrier = worse. r12: MORE work per barrier (BK=64) = -24us; all GEMMs < 95us.
// Per-op optima: fc1 BNT=128@1536; fc2 BNT=128 splitK2@768; outproj BNT=64@768.
// (256,4): reg cap 128 — no spill ((256,8) scratch catastrophe, r2).
#define KOFF 6291456ull
#define VOFF 13631488ull
template <int EPI, int BNT>
__global__ __launch_bounds__(256, 4) void gemm_bt(
    const unsigned short* __restrict__ A, const unsigned short* __restrict__ Bw,
    const float* __restrict__ bias, const float* __restrict__ resid,
    void* __restrict__ Cout, int M, int N, int K, int lda, int ldb, int NBN, int WM) {
  constexpr int NJ = BNT / 32;       // B-frags per wave; wave covers 16*NJ cols
  constexpr int BS = BNT * 32;       // u16 per B slab
  __shared__ __align__(16) unsigned short lA[2 * 128 * 32];  // [slab][128][32]
  __shared__ __align__(16) unsigned short lB[2 * BS];        // [slab][BNT][32]
  const int tid = threadIdx.x;
  const int w = tid >> 6, lane = tid & 63;
  const int lr = lane & 15, lq = lane >> 4;
  const int l = blockIdx.x;
  const int xcd = l & 7, r = l >> 3;
  const int bm = xcd * WM + (r % WM);
  const int rest = r / WM;
  const int bn = rest % NBN;
  const size_t koff = (size_t)(rest / NBN) * K;  // split-K offset (K = per-block K)
  const unsigned short* Ab = A + (size_t)bm * 128 * lda + koff;
  const unsigned short* Bb = Bw + (size_t)bn * BNT * ldb + koff;
  const int wm = (w & 1) << 6;
  const int wn = (w >> 1) * (16 * NJ);
  f32x4 acc[4][NJ] = {};
  const int kiters = K >> 6;         // BK=64
  const int c0 = tid, c1 = 256 + tid;
  const int r0 = c0 >> 2, o0 = (c0 & 3) << 3;
  const int r1 = c1 >> 2, o1 = (c1 & 3) << 3;
  for (int kt = 0; kt < kiters; ++kt) {
    const int kb = kt << 6;
    __syncthreads();
#pragma unroll
    for (int s = 0; s < 2; ++s) {
      const int kc = kb + s * 32;
      async16(Ab + (size_t)r0 * lda + kc + o0, lA + s * 4096 + c0 * 8);
      async16(Ab + (size_t)r1 * lda + kc + o1, lA + s * 4096 + c1 * 8);
      async16(Bb + (size_t)r0 * ldb + kc + o0, lB + s * BS + c0 * 8);
      if (BNT == 128) async16(Bb + (size_t)r1 * ldb + kc + o1, lB + s * BS + c1 * 8);
    }
    __syncthreads();
#pragma unroll
    for (int s = 0; s < 2; ++s) {
      bf16x8 af[4], bfr[NJ];
#pragma unroll
      for (int i = 0; i < 4; ++i)
        af[i] = *(const bf16x8*)(lA + s * 4096 + (wm + i * 16 + lr) * 32 + lq * 8);
#pragma unroll
      for (int j = 0; j < NJ; ++j)
        bfr[j] = *(const bf16x8*)(lB + s * BS + (wn + j * 16 + lr) * 32 + lq * 8);
#pragma unroll
      for (int i = 0; i < 4; ++i)
#pragma unroll
        for (int j = 0; j < NJ; ++j)
          acc[i][j] = __builtin_amdgcn_mfma_f32_16x16x32_bf16(af[i], bfr[j], acc[i][j], 0, 0, 0);
    }
  }
  const int which = (bn * BNT) >> 10;  // EPI5: 0=Q,1=K,2=V (block-uniform; 1024%BNT==0)
#pragma unroll
  for (int i = 0; i < 4; ++i) {
#pragma unroll
    for (int j = 0; j < NJ; ++j) {
      const int colg = bn * BNT + wn + j * 16 + lr;
      const float bi = (EPI == 6) ? 0.f : bias[colg];
      const int rowg0 = bm * 128 + wm + i * 16 + lq * 4;
#pragma unroll
      for (int r2 = 0; r2 < 4; ++r2) {
        const int rowg = rowg0 + r2;
        const float val = acc[i][j][r2] + bi;
        if (EPI == 5) {
          const int t = rowg >> 4, bb = rowg & 15;
          const int hh = (colg >> 6) & 15, dd = colg & 63;
          const size_t nn = (size_t)(bb * 16 + hh);
          unsigned short* q16 = (unsigned short*)Cout;
          if (which == 0) {
            if (rowg >= 1024) q16[(nn * 384 + (t - 64)) * 64 + dd] = f2bf(val);
          } else if (which == 1) {
            q16[KOFF + (nn * 448 + t) * 64 + dd] = f2bf(val);
          } else {
            q16[VOFF + (nn * 448 + t) * 64 + dd] = f2bf(val);
          }
        } else {
          const size_t idx = (size_t)rowg * N + colg;
          if (EPI == 2) ((float*)Cout)[idx] = val + resid[idx];
          else if (EPI == 3) ((unsigned short*)Cout)[idx] = f2bf(fmaxf(val, 0.f));
          else if (EPI == 6) atomicAdd(&((float*)Cout)[idx], acc[i][j][r2]);
        }
      }
    }
  }
}

// ---------------- V transpose: vb[n][t][d] -> vt[n][d][t] ----------------
__global__ __launch_bounds__(256) void vtrans(const unsigned short* __restrict__ vb,
                                              unsigned short* __restrict__ vt) {
  __shared__ __align__(16) unsigned short ls[64][80];
  const int kc = blockIdx.x, n = blockIdx.y;
  const int tid = threadIdx.x;
#pragma unroll
  for (int i = 0; i < 2; ++i) {
    const int c = i * 256 + tid;
    const int kk = c >> 3, dc = (c & 7) << 3;
    u16x8 val = *(const u16x8*)(vb + ((size_t)n * 448 + kc * 64 + kk) * 64 + dc);
    *(u16x8*)&ls[kk][dc] = val;
  }
  __syncthreads();
#pragma unroll
  for (int i = 0; i < 2; ++i) {
    const int c = i * 256 + tid;
    const int d = c >> 3, kx = (c & 7) << 3;
    u16x8 o;
#pragma unroll
    for (int j = 0; j < 8; ++j) o[j] = ls[kx + j][d];
    *(u16x8*)(vt + ((size_t)n * 64 + d) * 448 + kc * 64 + kx) = o;
  }
}

// ---------------- fused attention, S^T formulation, 4 waves/block, 2 q-tiles --------
// r13: variance pass via sum(p^2) identity (102->94.5). r14: deferred s2 norm +
// e-space mask (94.5->93.7, flat -> chain-shortening exhausted; latency-bound:
// VALU 31%, MFMA 5%, HBM 6%, all idle).
// ROUND 15: 2 q-tiles per block (same head n). K and V fragments loaded ONCE feed
// both tiles (global loads per tile halved); two independent softmax chains
// interleave (ILP under shuffle/LDS latency); 3 barriers amortize over 2 tiles.
// Grid 6144->3072. LDS 36.9KB (4 blk/CU), VGPR ~100 (5 waves/SIMD) — occupancy ok.
#define PST 468  // P row stride (u16): dword stride 234 == 10 mod 32 -> ~2-way (free)
__global__ __launch_bounds__(256) void attn_kernel(
    const unsigned short* __restrict__ qt_, const unsigned short* __restrict__ kt_,
    const unsigned short* __restrict__ vt_, unsigned short* __restrict__ attn) {
  __shared__ __align__(16) unsigned short P[32 * PST];  // 29952 B (2 q-tiles)
  __shared__ float Rm[4][32], Rs[4][32], Rc[4][32], Rv[4][32], R2[4][32];
  __shared__ __align__(16) float OT[4][16][17];         // per-wave transpose buffers
  const int id = blockIdx.x;
  const int xcd = id & 7, j0 = id >> 3;
  const int n = xcd * 32 + (j0 & 31), qt0 = (j0 >> 5) * 2;  // q-tiles qt0, qt0+1
  const int b = n >> 4, h = n & 15;
  const int tid = threadIdx.x, w = tid >> 6, lane = tid & 63;
  const int lr = lane & 15, lq = lane >> 4;

  const unsigned short* qpa = qt_ + ((size_t)n * 384 + qt0 * 16 + lr) * 64 + lq * 8;
  const bf16x8 qa0 = *(const bf16x8*)qpa;
  const bf16x8 qa1 = *(const bf16x8*)(qpa + 32);
  const unsigned short* qpb = qpa + 16 * 64;
  const bf16x8 qb0 = *(const bf16x8*)qpb;
  const bf16x8 qb1 = *(const bf16x8*)(qpb + 32);

  // phase 1: S^T for 7 k-tiles, both q-tiles off ONE K fragment load.
  f32x4 aca[7], acb[7];
#pragma unroll
  for (int t = 0; t < 7; ++t) {
    const unsigned short* kp = kt_ + ((size_t)n * 448 + (w * 7 + t) * 16 + lr) * 64 + lq * 8;
    const bf16x8 k0 = *(const bf16x8*)kp;
    const bf16x8 k1 = *(const bf16x8*)(kp + 32);
    f32x4 a = {0.f, 0.f, 0.f, 0.f}, bb2 = {0.f, 0.f, 0.f, 0.f};
    a = __builtin_amdgcn_mfma_f32_16x16x32_bf16(k0, qa0, a, 0, 0, 0);
    a = __builtin_amdgcn_mfma_f32_16x16x32_bf16(k1, qa1, a, 0, 0, 0);
    bb2 = __builtin_amdgcn_mfma_f32_16x16x32_bf16(k0, qb0, bb2, 0, 0, 0);
    bb2 = __builtin_amdgcn_mfma_f32_16x16x32_bf16(k1, qb1, bb2, 0, 0, 0);
    aca[t] = a; acb[t] = bb2;
  }

  // ---- pass 1: row max (both tiles, interleaved) ----
  f32x4 ma4 = aca[0], mb4 = acb[0];
#pragma unroll
  for (int t = 1; t < 7; ++t) {
#pragma unroll
    for (int r = 0; r < 4; ++r) {
      ma4[r] = fmaxf(ma4[r], aca[t][r]);
      mb4[r] = fmaxf(mb4[r], acb[t][r]);
    }
  }
  float ma = fmaxf(fmaxf(ma4[0], ma4[1]), fmaxf(ma4[2], ma4[3]));
  float mb = fmaxf(fmaxf(mb4[0], mb4[1]), fmaxf(mb4[2], mb4[3]));
  ma = fmaxf(ma, __shfl_xor(ma, 16)); mb = fmaxf(mb, __shfl_xor(mb, 16));
  ma = fmaxf(ma, __shfl_xor(ma, 32)); mb = fmaxf(mb, __shfl_xor(mb, 32));
  if (lq == 0) { Rm[w][lr] = ma; Rm[w][lr + 16] = mb; }
  __syncthreads();
  ma = fmaxf(fmaxf(Rm[0][lr], Rm[1][lr]), fmaxf(Rm[2][lr], Rm[3][lr]));
  mb = fmaxf(fmaxf(Rm[0][lr + 16], Rm[1][lr + 16]), fmaxf(Rm[2][lr + 16], Rm[3][lr + 16]));

  // ---- pass 2: exp in place; sum + nonzero count + sum of squares (both tiles) ----
  f32x4 sa4 = {0.f,0.f,0.f,0.f}, ca4 = {0.f,0.f,0.f,0.f}, qa4 = {0.f,0.f,0.f,0.f};
  f32x4 sb4 = {0.f,0.f,0.f,0.f}, cb4 = {0.f,0.f,0.f,0.f}, qb4 = {0.f,0.f,0.f,0.f};
#pragma unroll
  for (int t = 0; t < 7; ++t) {
#pragma unroll
    for (int r = 0; r < 4; ++r) {
      const float ea = __expf(aca[t][r] - ma);
      const float eb = __expf(acb[t][r] - mb);
      aca[t][r] = ea; acb[t][r] = eb;
      sa4[r] += ea; sb4[r] += eb;
      qa4[r] = fmaf(ea, ea, qa4[r]); qb4[r] = fmaf(eb, eb, qb4[r]);
      if (ea > 0.f) ca4[r] += 1.f;
      if (eb > 0.f) cb4[r] += 1.f;
    }
  }
  float sa = (sa4[0] + sa4[1]) + (sa4[2] + sa4[3]);
  float sb = (sb4[0] + sb4[1]) + (sb4[2] + sb4[3]);
  float ca = (ca4[0] + ca4[1]) + (ca4[2] + ca4[3]);
  float cb = (cb4[0] + cb4[1]) + (cb4[2] + cb4[3]);
  float ea2 = (qa4[0] + qa4[1]) + (qa4[2] + qa4[3]);
  float eb2 = (qb4[0] + qb4[1]) + (qb4[2] + qb4[3]);
  sa += __shfl_xor(sa, 16); sb += __shfl_xor(sb, 16);
  sa += __shfl_xor(sa, 32); sb += __shfl_xor(sb, 32);
  ca += __shfl_xor(ca, 16); cb += __shfl_xor(cb, 16);
  ca += __shfl_xor(ca, 32); cb += __shfl_xor(cb, 32);
  ea2 += __shfl_xor(ea2, 16); eb2 += __shfl_xor(eb2, 16);
  ea2 += __shfl_xor(ea2, 32); eb2 += __shfl_xor(eb2, 32);
  if (lq == 0) {
    Rs[w][lr] = sa; Rs[w][lr + 16] = sb;
    Rc[w][lr] = ca; Rc[w][lr + 16] = cb;
    Rv[w][lr] = ea2; Rv[w][lr + 16] = eb2;
  }
  __syncthreads();
  sa = (Rs[0][lr] + Rs[1][lr]) + (Rs[2][lr] + Rs[3][lr]);
  sb = (Rs[0][lr+16] + Rs[1][lr+16]) + (Rs[2][lr+16] + Rs[3][lr+16]);
  ca = (Rc[0][lr] + Rc[1][lr]) + (Rc[2][lr] + Rc[3][lr]);
  cb = (Rc[0][lr+16] + Rc[1][lr+16]) + (Rc[2][lr+16] + Rc[3][lr+16]);
  ea2 = (Rv[0][lr] + Rv[1][lr]) + (Rv[2][lr] + Rv[3][lr]);
  eb2 = (Rv[0][lr+16] + Rv[1][lr+16]) + (Rv[2][lr+16] + Rv[3][lr+16]);
  const float inva = 1.f / sa, invb = 1.f / sb;
  const float meana = 1.f / ca, meanb = 1.f / cb;
  // variance identity: sum_nz((p-mean)^2) = sum(p^2) - 1/cnt
  const float dva = fmaxf(ea2 * inva * inva - meana, 0.f);
  const float dvb = fmaxf(eb2 * invb * invb - meanb, 0.f);
  const float thra = (meana - 0.5f * sqrtf(dva / (ca - 1.f))) * sa;  // e-space
  const float thrb = (meanb - 0.5f * sqrtf(dvb / (cb - 1.f))) * sb;

  // ---- pass 3: mask survivors in place + survivor partial sums ----
  f32x4 ta4 = {0.f,0.f,0.f,0.f}, tb4 = {0.f,0.f,0.f,0.f};
#pragma unroll
  for (int t = 0; t < 7; ++t) {
#pragma unroll
    for (int r = 0; r < 4; ++r) {
      if (aca[t][r] < thra) aca[t][r] = 0.f;
      if (acb[t][r] < thrb) acb[t][r] = 0.f;
      ta4[r] += aca[t][r];
      tb4[r] += acb[t][r];
    }
  }
  float s2a = (ta4[0] + ta4[1]) + (ta4[2] + ta4[3]);
  float s2b = (tb4[0] + tb4[1]) + (tb4[2] + tb4[3]);
  s2a += __shfl_xor(s2a, 16); s2b += __shfl_xor(s2b, 16);
  s2a += __shfl_xor(s2a, 32); s2b += __shfl_xor(s2b, 32);
  if (lq == 0) { R2[w][lr] = s2a; R2[w][lr + 16] = s2b; }  // read after P barrier

  // ---- write P rows: tile a at [lr], tile b at [lr+16]; unnormalized masked e ----
#pragma unroll
  for (int t = 0; t < 7; ++t) {
#pragma unroll
    for (int rp = 0; rp < 4; rp += 2) {
      const int cidx = (w * 7 + t) * 16 + lq * 4 + rp;
      const unsigned int ua =
          (unsigned int)f2bf(aca[t][rp]) | ((unsigned int)f2bf(aca[t][rp + 1]) << 16);
      const unsigned int ub =
          (unsigned int)f2bf(acb[t][rp]) | ((unsigned int)f2bf(acb[t][rp + 1]) << 16);
      *(unsigned int*)&P[lr * PST + cidx] = ua;
      *(unsigned int*)&P[(lr + 16) * PST + cidx] = ub;
    }
  }
  __syncthreads();  // covers P and R2

  // phase 3: out^T[d][q] = V^T . P, both tiles off ONE V fragment load.
  f32x4 oa = {0.f, 0.f, 0.f, 0.f}, ob = {0.f, 0.f, 0.f, 0.f};
#pragma unroll
  for (int c = 0; c < 14; ++c) {
    union { ushort4 hh[2]; bf16x8 v; } pa, pb;
    pa.hh[0] = *(const ushort4*)&P[lr * PST + c * 32 + lq * 8];
    pa.hh[1] = *(const ushort4*)&P[lr * PST + c * 32 + lq * 8 + 4];
    pb.hh[0] = *(const ushort4*)&P[(lr + 16) * PST + c * 32 + lq * 8];
    pb.hh[1] = *(const ushort4*)&P[(lr + 16) * PST + c * 32 + lq * 8 + 4];
    const bf16x8 a = *(const bf16x8*)(vt_ + ((size_t)n * 64 + w * 16 + lr) * 448 + c * 32 + lq * 8);
    oa = __builtin_amdgcn_mfma_f32_16x16x32_bf16(a, pa.v, oa, 0, 0, 0);
    ob = __builtin_amdgcn_mfma_f32_16x16x32_bf16(a, pb.v, ob, 0, 0, 0);
  }

  // epilogue: transpose + deferred normalization, tile a then tile b (OT reused;
  // same-wave DS ops are in-order, no barrier needed).
  const int qrow = lane >> 2, dg = lane & 3;
#pragma unroll
  for (int r = 0; r < 4; ++r) OT[w][lq * 4 + r][lr] = oa[r];
  {
    const float s2t = (R2[0][qrow] + R2[1][qrow]) + (R2[2][qrow] + R2[3][qrow]);
    const float i2 = 1.f / s2t;
    ushort4 ov;
    ov.x = f2bf(OT[w][dg * 4 + 0][qrow] * i2);
    ov.y = f2bf(OT[w][dg * 4 + 1][qrow] * i2);
    ov.z = f2bf(OT[w][dg * 4 + 2][qrow] * i2);
    ov.w = f2bf(OT[w][dg * 4 + 3][qrow] * i2);
    *(ushort4*)(attn + ((size_t)(qt0 * 16 + qrow) * 16 + b) * 1024 + h * 64 + w * 16 + dg * 4) = ov;
  }
#pragma unroll
  for (int r = 0; r < 4; ++r) OT[w][lq * 4 + r][lr] = ob[r];
  {
    const float s2t = (R2[0][qrow + 16] + R2[1][qrow + 16]) + (R2[2][qrow + 16] + R2[3][qrow + 16]);
    const float i2 = 1.f / s2t;
    ushort4 ov;
    ov.x = f2bf(OT[w][dg * 4 + 0][qrow] * i2);
    ov.y = f2bf(OT[w][dg * 4 + 1][qrow] * i2);
    ov.z = f2bf(OT[w][dg * 4 + 2][qrow] * i2);
    ov.w = f2bf(OT[w][dg * 4 + 3][qrow] * i2);
    *(ushort4*)(attn + ((size_t)((qt0 + 1) * 16 + qrow) * 16 + b) * 1024 + h * 64 + w * 16 + dg * 4) = ov;
  }
}

// ---------------- launch ----------------
extern "C" void kernel_launch(void* const* d_in, const int* in_sizes, int n_in,
                              void* d_out, int out_size, void* d_ws, size_t ws_size,
                              hipStream_t stream) {
  (void)in_sizes; (void)n_in; (void)out_size; (void)ws_size;
  const float* x    = (const float*)d_in[0];
  const float* mem  = (const float*)d_in[1];
  const float* q_w  = (const float*)d_in[2];
  const float* q_b  = (const float*)d_in[3];
  const float* k_w  = (const float*)d_in[4];
  const float* k_b  = (const float*)d_in[5];
  const float* v_w  = (const float*)d_in[6];
  const float* v_b  = (const float*)d_in[7];
  const float* o_w  = (const float*)d_in[8];
  const float* o_b  = (const float*)d_in[9];
  const float* ln1w = (const float*)d_in[10];
  const float* ln1b = (const float*)d_in[11];
  const float* f1w  = (const float*)d_in[12];
  const float* f1b  = (const float*)d_in[13];
  const float* f2w  = (const float*)d_in[14];
  const float* f2b  = (const float*)d_in[15];
  const float* ln2w = (const float*)d_in[16];
  const float* ln2b = (const float*)d_in[17];

  unsigned short* WQ   = (unsigned short*)d_ws;        // 3x 1048576 contiguous = fused B
  unsigned short* WK   = WQ + 1048576;
  unsigned short* WV   = WK + 1048576;
  unsigned short* WO   = WV + 1048576;
  unsigned short* WF1  = WO + 1048576;                 // 4194304
  unsigned short* WF2  = WF1 + 4194304;                // 4194304
  unsigned short* ABUF = WF2 + 4194304;                // 7340032 (mem rows 0..1023, xn rows 1024..7167)
  unsigned short* QB   = ABUF + 7340032;               // 6291456 [n][384][64]; KB/VB at KOFF/VOFF
  unsigned short* KB   = QB + 6291456;                 // 7340032 [n][448][64]
  unsigned short* VB   = KB + 7340032;                 // 7340032 [n][448][64]
  unsigned short* VT   = VB + 7340032;                 // 7340032 [n][64][448]
  unsigned short* ATTN = VT + 7340032;                 // 6291456
  float*          X2   = (float*)(ATTN + 6291456);     // 6291456 f32
  float*          QKVB = (float*)ATTN;                 // 3072 f32, dead before attn writes ATTN
  unsigned short* XN2  = ATTN;                         // alias (attn dead after out-proj)
  unsigned short* HB   = ABUF;                         // alias (A/q/k/v staging dead after attention)

  // all weight/memory converts + bias concat in ONE launch
  cvt_all<<<13324, 256, 0, stream>>>(q_w, k_w, v_w, o_w, f1w, f2w, mem, q_b, k_b, v_b,
                                     WQ, WK, WV, WO, WF1, WF2, ABUF, QKVB);

  // LN1 -> xn (rows 1024.. of ABUF)
  ln_bf16<0><<<6144, 256, 0, stream>>>(x, ABUF + 1048576, ln1w, ln1b, nullptr, nullptr);

  // fused QKV: [mem;xn] x [Wq;Wk;Wv]^T, head-major epilogue. NBM=56 -> WM=7, NBN=24.
  gemm_bt<5, 128><<<1344, 256, 0, stream>>>(ABUF, WQ, QKVB, nullptr, QB, 7168, 3072, 1024, 1024, 1024, 24, 7);

  vtrans<<<dim3(7, 256), 256, 0, stream>>>(VB, VT);
  // attn: 2 q-tiles/block -> grid 3072 = 8 XCD x (32 n x 6 qt-pairs).
  attn_kernel<<<3072, 256, 0, stream>>>(QB, KB, VT, ATTN);

  // out-proj + residual -> X2 (f32). BNT=64: grid 768 = 8 XCD x (6 m x 16 n).
  gemm_bt<2, 64><<<768, 256, 0, stream>>>(ATTN, WO, o_b, x, X2, 6144, 1024, 1024, 1024, 1024, 16, 6);

  // LN2 -> xn2, and prefill d_out = X2 + fc2_bias (fc2 accumulates into it)
  ln_bf16<1><<<6144, 256, 0, stream>>>(X2, XN2, ln2w, ln2b, f2b, (float*)d_out);

  // FFN.
  // fc1: BNT=128, grid 1536 = 8 XCD x (6 m x 32 n).
  gemm_bt<3, 128><<<1536, 256, 0, stream>>>(XN2, WF1, f1b, nullptr, HB, 6144, 4096, 1024, 1024, 1024, 32, 6);
  // fc2: BNT=128, split-K 2, grid 768 = 8 XCD x (6 m x 8 n x 2 kz), per-block K=2048;
  //      atomicAdd f32 into ln2-prefilled d_out.
  gemm_bt<6, 128><<<768, 256, 0, stream>>>(HB, WF2, nullptr, nullptr, d_out, 6144, 1024, 2048, 4096, 4096, 8, 6);
}